// Round 9
// baseline (2988.643 us; speedup 1.0000x reference)
//
#include <hip/hip_runtime.h>
#include <hip/hip_bf16.h>

// GraphSAGE forward: proj -> [aggr -> gemm] x2 (+cls fused into gemm2)
// N=200000, E=3200000, IN_DIM=165, HID=64. All fp32.
//
// R9 design notes (post-mortem R8: proj 151us with VALUBusy 28% / HBM 17% /
// conflicts negligible -> phase serialization: stage(VALU idle) -> barrier ->
// compute(mem idle) x11. Floors: VALU 26us, LDS-pipe 40us, mem 29us.)
//  - All matmuls software-pipelined: prefetch chunk kc+1 into REGISTERS
//    during compute of kc (latency hidden behind FMAs), drain regs->LDS
//    between barriers, double-buffered x_s/w_s.
//  - Per-thread staging offsets precomputed once (no div/mod per chunk).
//  - SAGE gemm unified as K=128 GEMM [aggr|hin]@[Wl;Wr]: 8 chunks of BK=16,
//    source switched per chunk. Same 8x8 micro-tile everywhere.
//  - degree/scatter dst-range sharded + NT edge reads (R6/R8).

#define NNODES 200000
#define NEDGES 3200000
#define INDIM 165
#define HID 64

#define NR 8
#define RSIZE (NNODES / NR)
#define CHUNK_E 4096

#define SCAN_T 256
#define SCAN_I 8
#define SCAN_CHUNK (SCAN_T * SCAN_I)

#define BKP 15            // proj K chunk: 165 = 11*15
#define NCHP 11
#define BKG 16            // gemm K chunk: 128 = 8*16 (4 aggr + 4 hin)
#define NCHG 8
#define XT_STRIDE 260     // >=256 nodes, %4==0 (f4 aligned), %32==4 (bank rotate)

typedef float f4 __attribute__((ext_vector_type(4)));

#define RELU4(v) { v.x=fmaxf(v.x,0.f); v.y=fmaxf(v.y,0.f); v.z=fmaxf(v.z,0.f); v.w=fmaxf(v.w,0.f); }

// 8 nodes x 8 outs micro-tile FMA for one k
#define MT_FMA(xv0, xv1, wv0, wv1) \
  accA[0] += xv0.x * wv0; accB[0] += xv0.x * wv1; \
  accA[1] += xv0.y * wv0; accB[1] += xv0.y * wv1; \
  accA[2] += xv0.z * wv0; accB[2] += xv0.z * wv1; \
  accA[3] += xv0.w * wv0; accB[3] += xv0.w * wv1; \
  accA[4] += xv1.x * wv0; accB[4] += xv1.x * wv1; \
  accA[5] += xv1.y * wv0; accB[5] += xv1.y * wv1; \
  accA[6] += xv1.z * wv0; accB[6] += xv1.z * wv1; \
  accA[7] += xv1.w * wv0; accB[7] += xv1.w * wv1;

// ---------------- proj: h = relu(x @ Wp + bp) -----------------------------
// block = 256 nodes x 64 outs, thread = 8x8, double-buffered pipeline.
__global__ __launch_bounds__(256, 3)
void proj_kernel(const float* __restrict__ x,
                 const float* __restrict__ Wp,
                 const float* __restrict__ bp,
                 float* __restrict__ h, int n) {
  __shared__ float x_s[2][BKP * XT_STRIDE];  // 2 x 15,600 B
  __shared__ float w_s[2][BKP * HID];        // 2 x  3,840 B
  int t = threadIdx.x;
  int tx = t & 7;
  int ng = t >> 3;
  int n0 = blockIdx.x * 256;

  // precompute staging offsets (fixed across chunks)
  int xoff[BKP], soff[BKP];
  #pragma unroll
  for (int j = 0; j < BKP; ++j) {
    int i = t + 256 * j;
    int node = i / BKP, col = i - node * BKP;
    int gi = n0 + node; if (gi >= n) gi = n - 1;
    xoff[j] = gi * INDIM + col;
    soff[j] = col * XT_STRIDE + node;
  }
  bool wldr = (t < BKP * HID / 4);

  // prefetch + stage chunk 0
  float xr[BKP];
  f4 wr;
  #pragma unroll
  for (int j = 0; j < BKP; ++j) xr[j] = x[xoff[j]];
  if (wldr) wr = ((const f4*)Wp)[t];
  #pragma unroll
  for (int j = 0; j < BKP; ++j) x_s[0][soff[j]] = xr[j];
  if (wldr) ((f4*)w_s[0])[t] = wr;
  __syncthreads();

  f4 b0 = ((const f4*)bp)[tx * 2];
  f4 b1 = ((const f4*)bp)[tx * 2 + 1];
  f4 accA[8], accB[8];
  #pragma unroll
  for (int i = 0; i < 8; ++i) { accA[i] = b0; accB[i] = b1; }

  for (int kc = 0; kc < NCHP; ++kc) {
    int cur = kc & 1, nxt = cur ^ 1;
    if (kc + 1 < NCHP) {
      #pragma unroll
      for (int j = 0; j < BKP; ++j) xr[j] = x[xoff[j] + (kc + 1) * BKP];
      if (wldr) wr = ((const f4*)(Wp + (kc + 1) * BKP * HID))[t];
    }
    #pragma unroll
    for (int k = 0; k < BKP; ++k) {
      const float* xrr = &x_s[cur][k * XT_STRIDE + ng * 8];
      f4 xv0 = *(const f4*)xrr;
      f4 xv1 = *(const f4*)(xrr + 4);
      f4 wv0 = *(const f4*)&w_s[cur][k * HID + tx * 8];
      f4 wv1 = *(const f4*)&w_s[cur][k * HID + tx * 8 + 4];
      MT_FMA(xv0, xv1, wv0, wv1)
    }
    __syncthreads();
    if (kc + 1 < NCHP) {
      #pragma unroll
      for (int j = 0; j < BKP; ++j) x_s[nxt][soff[j]] = xr[j];
      if (wldr) ((f4*)w_s[nxt])[t] = wr;
      __syncthreads();
    }
  }
  #pragma unroll
  for (int i = 0; i < 8; ++i) {
    int node = n0 + ng * 8 + i;
    if (node < n) {
      f4 a = accA[i], b = accB[i];
      RELU4(a) RELU4(b)
      *(f4*)&h[(size_t)node * HID + tx * 8] = a;
      *(f4*)&h[(size_t)node * HID + tx * 8 + 4] = b;
    }
  }
}

// ---------------- degree histogram (sharded + NT edge reads) --------------
__global__ void degree_kernel(const int* __restrict__ dst, int* __restrict__ counts, int e) {
  int r = blockIdx.x & (NR - 1);
  int chunk = blockIdx.x / NR;
  int lo = r * RSIZE, hi = lo + RSIZE;
  int base = chunk * CHUNK_E;
  int end = min(base + CHUNK_E, e);
  for (int i = base + (int)threadIdx.x; i < end; i += 256) {
    int d = __builtin_nontemporal_load(&dst[i]);
    if (d >= lo && d < hi) atomicAdd(&counts[d], 1);
  }
}

// ---------------- scan ----------------------------------------------------
__global__ void scan1_kernel(const int* __restrict__ counts, int* __restrict__ row_ptr,
                             int* __restrict__ bsums, int n) {
  __shared__ int lds[SCAN_T];
  int b = blockIdx.x, t = threadIdx.x;
  int base = b * SCAN_CHUNK + t * SCAN_I;
  int v[SCAN_I];
  int s = 0;
  #pragma unroll
  for (int i = 0; i < SCAN_I; ++i) {
    int idx = base + i;
    v[i] = (idx < n) ? counts[idx] : 0;
    s += v[i];
  }
  lds[t] = s;
  __syncthreads();
  for (int off = 1; off < SCAN_T; off <<= 1) {
    int y = (t >= off) ? lds[t - off] : 0;
    __syncthreads();
    lds[t] += y;
    __syncthreads();
  }
  int incl = lds[t];
  int run = incl - s;
  #pragma unroll
  for (int i = 0; i < SCAN_I; ++i) {
    int idx = base + i;
    if (idx < n) row_ptr[idx] = run;
    run += v[i];
  }
  if (t == SCAN_T - 1) bsums[b] = incl;
}

__global__ void scan2_kernel(int* __restrict__ bsums, int nb) {
  __shared__ int lds[SCAN_T];
  int t = threadIdx.x;
  int v = (t < nb) ? bsums[t] : 0;
  lds[t] = v;
  __syncthreads();
  for (int off = 1; off < SCAN_T; off <<= 1) {
    int y = (t >= off) ? lds[t - off] : 0;
    __syncthreads();
    lds[t] += y;
    __syncthreads();
  }
  if (t < nb) bsums[t] = lds[t] - v;
}

__global__ void scan3_kernel(int* __restrict__ row_ptr, const int* __restrict__ bsums,
                             int* __restrict__ cursor, int n, int e) {
  int i = blockIdx.x * blockDim.x + threadIdx.x;
  if (i < n) {
    int v = row_ptr[i] + bsums[i / SCAN_CHUNK];
    row_ptr[i] = v;
    cursor[i] = v;
  }
  if (i == n) row_ptr[n] = e;
}

// ---------------- scatter into CSR (sharded + NT edge reads) --------------
__global__ void scatter_kernel(const int* __restrict__ src, const int* __restrict__ dst,
                               int* __restrict__ cursor, int* __restrict__ csr_src, int e) {
  int r = blockIdx.x & (NR - 1);
  int chunk = blockIdx.x / NR;
  int lo = r * RSIZE, hi = lo + RSIZE;
  int base = chunk * CHUNK_E;
  int end = min(base + CHUNK_E, e);
  for (int i = base + (int)threadIdx.x; i < end; i += 256) {
    int d = __builtin_nontemporal_load(&dst[i]);
    if (d >= lo && d < hi) {
      int s = __builtin_nontemporal_load(&src[i]);
      int pos = atomicAdd(&cursor[d], 1);
      csr_src[pos] = s;
    }
  }
}

// ---------------- mean aggregation (pull, CSR) ----------------------------
__global__ void aggr_kernel(const float* __restrict__ hin,
                            const int* __restrict__ row_ptr,
                            const int* __restrict__ csr_src,
                            float* __restrict__ aggr, int n) {
  int lane = threadIdx.x & 63;
  int grp = lane >> 4, sub = lane & 15;
  int node = (blockIdx.x * blockDim.x + threadIdx.x) >> 6;
  if (node >= n) return;
  int r0 = row_ptr[node], r1 = row_ptr[node + 1];
  f4 acc0 = {0.f, 0.f, 0.f, 0.f}, acc1 = {0.f, 0.f, 0.f, 0.f};
  int p = r0;
  for (; p + 8 <= r1; p += 8) {
    int i0 = csr_src[p + grp];
    int i1 = csr_src[p + 4 + grp];
    f4 v0 = *((const f4*)(hin + (size_t)i0 * HID) + sub);
    f4 v1 = *((const f4*)(hin + (size_t)i1 * HID) + sub);
    acc0 += v0;
    acc1 += v1;
  }
  if (p + 4 <= r1) {
    int i0 = csr_src[p + grp];
    acc0 += *((const f4*)(hin + (size_t)i0 * HID) + sub);
    p += 4;
  }
  int rem = r1 - p;
  if (grp < rem) {
    int i0 = csr_src[p + grp];
    acc1 += *((const f4*)(hin + (size_t)i0 * HID) + sub);
  }
  acc0 += acc1;
  #pragma unroll
  for (int c = 0; c < 4; ++c) {
    float v = acc0[c];
    v += __shfl_xor(v, 16, 64);
    v += __shfl_xor(v, 32, 64);
    acc0[c] = v;
  }
  int deg = r1 - r0;
  float rdeg = 1.f / (float)(deg > 1 ? deg : 1);
  if (grp == 0) {
    f4 o = acc0 * rdeg;
    *((f4*)(aggr + (size_t)node * HID) + sub) = o;
  }
}

// ---------------- gemm: hout = relu([aggr|hin] @ [Wl;Wr] + bl) ------------
// K=128 unified, 8 chunks of 16 (chunks 0-3 from aggr/Wl, 4-7 from hin/Wr),
// double-buffered pipeline identical to proj. In-place hout==hin safe:
// hin global reads all happen during prefetch (before last compute barrier),
// each block touches only its own 256 rows.

#define GEMM_PIPE(aggrp, hinp) \
  int goff[BKG], soff[BKG]; \
  { \
    int kk = t & 15, nb = t >> 4; \
    _Pragma("unroll") \
    for (int j = 0; j < BKG; ++j) { \
      int node = nb + 16 * j; \
      int gi = n0 + node; if (gi >= n) gi = n - 1; \
      goff[j] = gi * HID + kk; \
      soff[j] = kk * XT_STRIDE + node; \
    } \
  } \
  float xr[BKG]; \
  f4 wr; \
  _Pragma("unroll") \
  for (int j = 0; j < BKG; ++j) xr[j] = aggrp[goff[j]]; \
  wr = ((const f4*)Wl)[t]; \
  _Pragma("unroll") \
  for (int j = 0; j < BKG; ++j) x_s[0][soff[j]] = xr[j]; \
  ((f4*)w_s[0])[t] = wr; \
  __syncthreads(); \
  f4 b0 = ((const f4*)bl)[tx * 2]; \
  f4 b1 = ((const f4*)bl)[tx * 2 + 1]; \
  f4 accA[8], accB[8]; \
  _Pragma("unroll") \
  for (int i = 0; i < 8; ++i) { accA[i] = b0; accB[i] = b1; } \
  for (int kc = 0; kc < NCHG; ++kc) { \
    int cur = kc & 1, nxt = cur ^ 1; \
    if (kc + 1 < NCHG) { \
      int kn = kc + 1; \
      const float* xsrc = (kn < 4) ? aggrp : hinp; \
      const float* wsrc = (kn < 4) ? Wl : Wr; \
      int kof = (kn & 3) * BKG; \
      _Pragma("unroll") \
      for (int j = 0; j < BKG; ++j) xr[j] = xsrc[goff[j] + kof]; \
      wr = ((const f4*)(wsrc + kof * HID))[t]; \
    } \
    _Pragma("unroll") \
    for (int k = 0; k < BKG; ++k) { \
      const float* xrr = &x_s[cur][k * XT_STRIDE + ng * 8]; \
      f4 xv0 = *(const f4*)xrr; \
      f4 xv1 = *(const f4*)(xrr + 4); \
      f4 wv0 = *(const f4*)&w_s[cur][k * HID + tx * 8]; \
      f4 wv1 = *(const f4*)&w_s[cur][k * HID + tx * 8 + 4]; \
      MT_FMA(xv0, xv1, wv0, wv1) \
    } \
    __syncthreads(); \
    if (kc + 1 < NCHG) { \
      _Pragma("unroll") \
      for (int j = 0; j < BKG; ++j) x_s[nxt][soff[j]] = xr[j]; \
      ((f4*)w_s[nxt])[t] = wr; \
      __syncthreads(); \
    } \
  }

__global__ __launch_bounds__(256, 3)
void gemm_kernel(const float* __restrict__ aggr,
                 const float* hin,
                 const float* __restrict__ Wl, const float* __restrict__ bl,
                 const float* __restrict__ Wr,
                 float* hout, int n) {
  __shared__ float x_s[2][BKG * XT_STRIDE];  // 2 x 16,640 B
  __shared__ float w_s[2][BKG * HID];        // 2 x  4,096 B
  int t = threadIdx.x;
  int tx = t & 7;
  int ng = t >> 3;
  int n0 = blockIdx.x * 256;

  GEMM_PIPE(aggr, hin)

  #pragma unroll
  for (int i = 0; i < 8; ++i) {
    int node = n0 + ng * 8 + i;
    if (node < n) {
      f4 a = accA[i], b = accB[i];
      RELU4(a) RELU4(b)
      *(f4*)&hout[(size_t)node * HID + tx * 8] = a;
      *(f4*)&hout[(size_t)node * HID + tx * 8 + 4] = b;
    }
  }
}

// ---------------- gemm2 + cls fused ---------------------------------------
__global__ __launch_bounds__(256, 3)
void gemm_cls_kernel(const float* __restrict__ aggr,
                     const float* __restrict__ hin,
                     const float* __restrict__ Wl, const float* __restrict__ bl,
                     const float* __restrict__ Wr,
                     const float* __restrict__ Wc, const float* __restrict__ bc,
                     float* __restrict__ out, int n) {
  __shared__ float x_s[2][BKG * XT_STRIDE];
  __shared__ float w_s[2][BKG * HID];
  int t = threadIdx.x;
  int tx = t & 7;
  int ng = t >> 3;
  int n0 = blockIdx.x * 256;

  GEMM_PIPE(aggr, hin)

  f4 wc0 = ((const f4*)Wc)[tx * 2];
  f4 wc1 = ((const f4*)Wc)[tx * 2 + 1];
  float bcv = bc[0];
  #pragma unroll
  for (int i = 0; i < 8; ++i) {
    f4 a = accA[i], b = accB[i];
    RELU4(a) RELU4(b)
    float s = a.x * wc0.x + a.y * wc0.y + a.z * wc0.z + a.w * wc0.w
            + b.x * wc1.x + b.y * wc1.y + b.z * wc1.z + b.w * wc1.w;
    s += __shfl_xor(s, 1, 64);
    s += __shfl_xor(s, 2, 64);
    s += __shfl_xor(s, 4, 64);
    int node = n0 + ng * 8 + i;
    if (tx == 0 && node < n) out[node] = s + bcv;
  }
}

extern "C" void kernel_launch(void* const* d_in, const int* in_sizes, int n_in,
                              void* d_out, int out_size, void* d_ws, size_t ws_size,
                              hipStream_t stream) {
  const float* x   = (const float*)d_in[0];
  const int*   ei  = (const int*)d_in[1];
  const float* Wp  = (const float*)d_in[2];
  const float* bp  = (const float*)d_in[3];
  const float* W1l = (const float*)d_in[4];
  const float* b1l = (const float*)d_in[5];
  const float* W1r = (const float*)d_in[6];
  const float* W2l = (const float*)d_in[7];
  const float* b2l = (const float*)d_in[8];
  const float* W2r = (const float*)d_in[9];
  const float* Wc  = (const float*)d_in[10];
  const float* bc  = (const float*)d_in[11];
  float* out = (float*)d_out;

  const int N = NNODES, E = NEDGES;
  const int* src = ei;
  const int* dst = ei + E;

  char* ws = (char*)d_ws;
  float* h       = (float*)(ws + 0);
  float* aggr    = (float*)(ws + 51200000);
  int*   counts  = (int*)  (ws + 102400000);
  int*   row_ptr = (int*)  (ws + 103200000);
  int*   cursor  = (int*)  (ws + 104000256);
  int*   csr_src = (int*)  (ws + 104800256);
  int*   bsums   = (int*)  (ws + 117600256);

  hipMemsetAsync(counts, 0, (size_t)N * 4, stream);

  proj_kernel<<<782, 256, 0, stream>>>(x, Wp, bp, h, N);

  int nchunks = (E + CHUNK_E - 1) / CHUNK_E;
  degree_kernel<<<nchunks * NR, 256, 0, stream>>>(dst, counts, E);
  int nb = (N + SCAN_CHUNK - 1) / SCAN_CHUNK;
  scan1_kernel<<<nb, SCAN_T, 0, stream>>>(counts, row_ptr, bsums, N);
  scan2_kernel<<<1, SCAN_T, 0, stream>>>(bsums, nb);
  scan3_kernel<<<(N + 256) / 256, 256, 0, stream>>>(row_ptr, bsums, cursor, N, E);
  scatter_kernel<<<nchunks * NR, 256, 0, stream>>>(src, dst, cursor, csr_src, E);

  aggr_kernel<<<(N + 3) / 4, 256, 0, stream>>>(h, row_ptr, csr_src, aggr, N);
  gemm_kernel<<<782, 256, 0, stream>>>(aggr, h, W1l, b1l, W1r, h, N);

  aggr_kernel<<<(N + 3) / 4, 256, 0, stream>>>(h, row_ptr, csr_src, aggr, N);
  gemm_cls_kernel<<<782, 256, 0, stream>>>(aggr, h, W2l, b2l, W2r, Wc, bc, out, N);
}

// Round 11
// 1333.686 us; speedup vs baseline: 2.2409x; 2.2409x over previous
//
#include <hip/hip_runtime.h>
#include <hip/hip_bf16.h>

// GraphSAGE forward: proj -> [aggr -> gemm] x2 (+cls fused into gemm2)
// N=200000, E=3200000, IN_DIM=165, HID=64. All fp32.
//
// R11 design notes (post-mortem R10: DMA pipeline raced — passed first
// launch, diverged under graph replay. __syncthreads() is NOT guaranteed to
// drain global_load_lds (tracked in vmcnt, not lgkmcnt); m97's observed
// vmcnt(0)-before-s_barrier is compiler behavior, not a contract. Fix:
// explicit s_waitcnt vmcnt(0) [imm 0xF70] before every barrier that must
// see DMA results. Everything else identical to R10.)
//  - async global->LDS DMA double-buffer (zero VGPR staging; R9's spill
//    structurally impossible). Stride-256 transposed tiles, slot = t+256j ->
//    lane-contiguous LDS as the DMA requires; 2-way bank aliasing = free.
//  - SAGE gemm = unified K=128 GEMM [aggr|hin]@[Wl;Wr], 8 chunks of 16.
//  - degree/scatter dst-range sharded + NT edge reads (R6/R8).

#define NNODES 200000
#define NEDGES 3200000
#define INDIM 165
#define HID 64

#define NR 8
#define RSIZE (NNODES / NR)
#define CHUNK_E 4096

#define SCAN_T 256
#define SCAN_I 8
#define SCAN_CHUNK (SCAN_T * SCAN_I)

#define BKP 15            // proj K chunk: 165 = 11*15
#define NCHP 11
#define BKG 16            // gemm K chunk: 128 = 8*16 (4 aggr + 4 hin)
#define NCHG 8

typedef float f4 __attribute__((ext_vector_type(4)));

#define RELU4(v) { v.x=fmaxf(v.x,0.f); v.y=fmaxf(v.y,0.f); v.z=fmaxf(v.z,0.f); v.w=fmaxf(v.w,0.f); }

// async 4B global->LDS copy (DMA, no VGPR round-trip)
__device__ __forceinline__ void async4(const float* g, float* l) {
  __builtin_amdgcn_global_load_lds(
      (const __attribute__((address_space(1))) void*)g,
      (__attribute__((address_space(3))) void*)l, 4, 0, 0);
}

// drain outstanding global ops (incl. LDS-DMA): s_waitcnt vmcnt(0)
// imm encoding: lgkmcnt=15 (0xF00) | expcnt=7 (0x70) | vmcnt=0 -> 0xF70
__device__ __forceinline__ void dma_drain() {
  __builtin_amdgcn_s_waitcnt(0xF70);
}

// 8 nodes x 8 outs micro-tile FMA for one k
#define MT_FMA(xv0, xv1, wv0, wv1) \
  accA[0] += xv0.x * wv0; accB[0] += xv0.x * wv1; \
  accA[1] += xv0.y * wv0; accB[1] += xv0.y * wv1; \
  accA[2] += xv0.z * wv0; accB[2] += xv0.z * wv1; \
  accA[3] += xv0.w * wv0; accB[3] += xv0.w * wv1; \
  accA[4] += xv1.x * wv0; accB[4] += xv1.x * wv1; \
  accA[5] += xv1.y * wv0; accB[5] += xv1.y * wv1; \
  accA[6] += xv1.z * wv0; accB[6] += xv1.z * wv1; \
  accA[7] += xv1.w * wv0; accB[7] += xv1.w * wv1;

// ---------------- proj: h = relu(x @ Wp + bp) -----------------------------
// block = 256 nodes x 64 outs, thread = 8x8; async-DMA double-buffer.
__global__ __launch_bounds__(256, 3)
void proj_kernel(const float* __restrict__ x,
                 const float* __restrict__ Wp,
                 const float* __restrict__ bp,
                 float* __restrict__ h, int n) {
  __shared__ float x_s[2][BKP * 256];   // 2 x 15,360 B
  __shared__ float w_s[2][BKP * HID];   // 2 x  3,840 B
  int t = threadIdx.x;
  int tx = t & 7;
  int ng = t >> 3;
  int n0 = blockIdx.x * 256;
  int gi = n0 + t; if (gi >= n) gi = n - 1;
  const float* xrow = x + (size_t)gi * INDIM;

  // stage chunk 0 into buf 0
  #pragma unroll
  for (int j = 0; j < BKP; ++j) async4(xrow + j, &x_s[0][j * 256 + t]);
  #pragma unroll
  for (int j = 0; j < 3; ++j) async4(Wp + t + 256 * j, &w_s[0][t + 256 * j]);
  if (t < BKP * HID - 768) async4(Wp + t + 768, &w_s[0][t + 768]);
  dma_drain();
  __syncthreads();

  f4 b0 = ((const f4*)bp)[tx * 2];
  f4 b1 = ((const f4*)bp)[tx * 2 + 1];
  f4 accA[8], accB[8];
  #pragma unroll
  for (int i = 0; i < 8; ++i) { accA[i] = b0; accB[i] = b1; }

  for (int kc = 0; kc < NCHP; ++kc) {
    int cur = kc & 1, nxt = cur ^ 1;
    if (kc + 1 < NCHP) {
      const float* xsrc = xrow + (kc + 1) * BKP;
      const float* wsrc = Wp + (kc + 1) * BKP * HID;
      #pragma unroll
      for (int j = 0; j < BKP; ++j) async4(xsrc + j, &x_s[nxt][j * 256 + t]);
      #pragma unroll
      for (int j = 0; j < 3; ++j) async4(wsrc + t + 256 * j, &w_s[nxt][t + 256 * j]);
      if (t < BKP * HID - 768) async4(wsrc + t + 768, &w_s[nxt][t + 768]);
    }
    #pragma unroll
    for (int k = 0; k < BKP; ++k) {
      const float* xrr = &x_s[cur][k * 256 + ng * 8];
      f4 xv0 = *(const f4*)xrr;
      f4 xv1 = *(const f4*)(xrr + 4);
      f4 wv0 = *(const f4*)&w_s[cur][k * HID + tx * 8];
      f4 wv1 = *(const f4*)&w_s[cur][k * HID + tx * 8 + 4];
      MT_FMA(xv0, xv1, wv0, wv1)
    }
    dma_drain();       // DMA for chunk kc+1 fully landed
    __syncthreads();   // all waves done reading cur + DMA visible
  }
  #pragma unroll
  for (int i = 0; i < 8; ++i) {
    int node = n0 + ng * 8 + i;
    if (node < n) {
      f4 a = accA[i], b = accB[i];
      RELU4(a) RELU4(b)
      *(f4*)&h[(size_t)node * HID + tx * 8] = a;
      *(f4*)&h[(size_t)node * HID + tx * 8 + 4] = b;
    }
  }
}

// ---------------- degree histogram (sharded + NT edge reads) --------------
__global__ void degree_kernel(const int* __restrict__ dst, int* __restrict__ counts, int e) {
  int r = blockIdx.x & (NR - 1);
  int chunk = blockIdx.x / NR;
  int lo = r * RSIZE, hi = lo + RSIZE;
  int base = chunk * CHUNK_E;
  int end = min(base + CHUNK_E, e);
  for (int i = base + (int)threadIdx.x; i < end; i += 256) {
    int d = __builtin_nontemporal_load(&dst[i]);
    if (d >= lo && d < hi) atomicAdd(&counts[d], 1);
  }
}

// ---------------- scan ----------------------------------------------------
__global__ void scan1_kernel(const int* __restrict__ counts, int* __restrict__ row_ptr,
                             int* __restrict__ bsums, int n) {
  __shared__ int lds[SCAN_T];
  int b = blockIdx.x, t = threadIdx.x;
  int base = b * SCAN_CHUNK + t * SCAN_I;
  int v[SCAN_I];
  int s = 0;
  #pragma unroll
  for (int i = 0; i < SCAN_I; ++i) {
    int idx = base + i;
    v[i] = (idx < n) ? counts[idx] : 0;
    s += v[i];
  }
  lds[t] = s;
  __syncthreads();
  for (int off = 1; off < SCAN_T; off <<= 1) {
    int y = (t >= off) ? lds[t - off] : 0;
    __syncthreads();
    lds[t] += y;
    __syncthreads();
  }
  int incl = lds[t];
  int run = incl - s;
  #pragma unroll
  for (int i = 0; i < SCAN_I; ++i) {
    int idx = base + i;
    if (idx < n) row_ptr[idx] = run;
    run += v[i];
  }
  if (t == SCAN_T - 1) bsums[b] = incl;
}

__global__ void scan2_kernel(int* __restrict__ bsums, int nb) {
  __shared__ int lds[SCAN_T];
  int t = threadIdx.x;
  int v = (t < nb) ? bsums[t] : 0;
  lds[t] = v;
  __syncthreads();
  for (int off = 1; off < SCAN_T; off <<= 1) {
    int y = (t >= off) ? lds[t - off] : 0;
    __syncthreads();
    lds[t] += y;
    __syncthreads();
  }
  if (t < nb) bsums[t] = lds[t] - v;
}

__global__ void scan3_kernel(int* __restrict__ row_ptr, const int* __restrict__ bsums,
                             int* __restrict__ cursor, int n, int e) {
  int i = blockIdx.x * blockDim.x + threadIdx.x;
  if (i < n) {
    int v = row_ptr[i] + bsums[i / SCAN_CHUNK];
    row_ptr[i] = v;
    cursor[i] = v;
  }
  if (i == n) row_ptr[n] = e;
}

// ---------------- scatter into CSR (sharded + NT edge reads) --------------
__global__ void scatter_kernel(const int* __restrict__ src, const int* __restrict__ dst,
                               int* __restrict__ cursor, int* __restrict__ csr_src, int e) {
  int r = blockIdx.x & (NR - 1);
  int chunk = blockIdx.x / NR;
  int lo = r * RSIZE, hi = lo + RSIZE;
  int base = chunk * CHUNK_E;
  int end = min(base + CHUNK_E, e);
  for (int i = base + (int)threadIdx.x; i < end; i += 256) {
    int d = __builtin_nontemporal_load(&dst[i]);
    if (d >= lo && d < hi) {
      int s = __builtin_nontemporal_load(&src[i]);
      int pos = atomicAdd(&cursor[d], 1);
      csr_src[pos] = s;
    }
  }
}

// ---------------- mean aggregation (pull, CSR) ----------------------------
__global__ void aggr_kernel(const float* __restrict__ hin,
                            const int* __restrict__ row_ptr,
                            const int* __restrict__ csr_src,
                            float* __restrict__ aggr, int n) {
  int lane = threadIdx.x & 63;
  int grp = lane >> 4, sub = lane & 15;
  int node = (blockIdx.x * blockDim.x + threadIdx.x) >> 6;
  if (node >= n) return;
  int r0 = row_ptr[node], r1 = row_ptr[node + 1];
  f4 acc0 = {0.f, 0.f, 0.f, 0.f}, acc1 = {0.f, 0.f, 0.f, 0.f};
  int p = r0;
  for (; p + 8 <= r1; p += 8) {
    int i0 = csr_src[p + grp];
    int i1 = csr_src[p + 4 + grp];
    f4 v0 = *((const f4*)(hin + (size_t)i0 * HID) + sub);
    f4 v1 = *((const f4*)(hin + (size_t)i1 * HID) + sub);
    acc0 += v0;
    acc1 += v1;
  }
  if (p + 4 <= r1) {
    int i0 = csr_src[p + grp];
    acc0 += *((const f4*)(hin + (size_t)i0 * HID) + sub);
    p += 4;
  }
  int rem = r1 - p;
  if (grp < rem) {
    int i0 = csr_src[p + grp];
    acc1 += *((const f4*)(hin + (size_t)i0 * HID) + sub);
  }
  acc0 += acc1;
  #pragma unroll
  for (int c = 0; c < 4; ++c) {
    float v = acc0[c];
    v += __shfl_xor(v, 16, 64);
    v += __shfl_xor(v, 32, 64);
    acc0[c] = v;
  }
  int deg = r1 - r0;
  float rdeg = 1.f / (float)(deg > 1 ? deg : 1);
  if (grp == 0) {
    f4 o = acc0 * rdeg;
    *((f4*)(aggr + (size_t)node * HID) + sub) = o;
  }
}

// ---------------- gemm: hout = relu([aggr|hin] @ [Wl;Wr] + bl) ------------
// K=128 unified (chunks 0-3 aggr/Wl, 4-7 hin/Wr), async-DMA double-buffer.
// In-place hout==hin safe: each block reads only its own 256 rows.

#define GEMM_STAGE_CH(kn, buf) { \
    const float* xsrc = ((kn) < 4) ? arow : hrow; \
    const float* wsrc = ((kn) < 4) ? Wl : Wr; \
    int kof = ((kn) & 3) * BKG; \
    _Pragma("unroll") \
    for (int j = 0; j < BKG; ++j) async4(xsrc + kof + j, &x_s[buf][j * 256 + t]); \
    _Pragma("unroll") \
    for (int j = 0; j < 4; ++j) async4(wsrc + kof * HID + t + 256 * j, &w_s[buf][t + 256 * j]); \
  }

#define GEMM_PIPE() \
  GEMM_STAGE_CH(0, 0) \
  dma_drain(); \
  __syncthreads(); \
  f4 b0 = ((const f4*)bl)[tx * 2]; \
  f4 b1 = ((const f4*)bl)[tx * 2 + 1]; \
  f4 accA[8], accB[8]; \
  _Pragma("unroll") \
  for (int i = 0; i < 8; ++i) { accA[i] = b0; accB[i] = b1; } \
  for (int kc = 0; kc < NCHG; ++kc) { \
    int cur = kc & 1, nxt = cur ^ 1; \
    if (kc + 1 < NCHG) GEMM_STAGE_CH(kc + 1, nxt) \
    _Pragma("unroll") \
    for (int k = 0; k < BKG; ++k) { \
      const float* xrr = &x_s[cur][k * 256 + ng * 8]; \
      f4 xv0 = *(const f4*)xrr; \
      f4 xv1 = *(const f4*)(xrr + 4); \
      f4 wv0 = *(const f4*)&w_s[cur][k * HID + tx * 8]; \
      f4 wv1 = *(const f4*)&w_s[cur][k * HID + tx * 8 + 4]; \
      MT_FMA(xv0, xv1, wv0, wv1) \
    } \
    dma_drain(); \
    __syncthreads(); \
  }

__global__ __launch_bounds__(256, 3)
void gemm_kernel(const float* __restrict__ aggr,
                 const float* hin,
                 const float* __restrict__ Wl, const float* __restrict__ bl,
                 const float* __restrict__ Wr,
                 float* hout, int n) {
  __shared__ float x_s[2][BKG * 256];   // 2 x 16,384 B
  __shared__ float w_s[2][BKG * HID];   // 2 x  4,096 B
  int t = threadIdx.x;
  int tx = t & 7;
  int ng = t >> 3;
  int n0 = blockIdx.x * 256;
  int gi = n0 + t; if (gi >= n) gi = n - 1;
  const float* arow = aggr + (size_t)gi * HID;
  const float* hrow = hin + (size_t)gi * HID;

  GEMM_PIPE()

  #pragma unroll
  for (int i = 0; i < 8; ++i) {
    int node = n0 + ng * 8 + i;
    if (node < n) {
      f4 a = accA[i], b = accB[i];
      RELU4(a) RELU4(b)
      *(f4*)&hout[(size_t)node * HID + tx * 8] = a;
      *(f4*)&hout[(size_t)node * HID + tx * 8 + 4] = b;
    }
  }
}

// ---------------- gemm2 + cls fused ---------------------------------------
__global__ __launch_bounds__(256, 3)
void gemm_cls_kernel(const float* __restrict__ aggr,
                     const float* __restrict__ hin,
                     const float* __restrict__ Wl, const float* __restrict__ bl,
                     const float* __restrict__ Wr,
                     const float* __restrict__ Wc, const float* __restrict__ bc,
                     float* __restrict__ out, int n) {
  __shared__ float x_s[2][BKG * 256];
  __shared__ float w_s[2][BKG * HID];
  int t = threadIdx.x;
  int tx = t & 7;
  int ng = t >> 3;
  int n0 = blockIdx.x * 256;
  int gi = n0 + t; if (gi >= n) gi = n - 1;
  const float* arow = aggr + (size_t)gi * HID;
  const float* hrow = hin + (size_t)gi * HID;

  GEMM_PIPE()

  f4 wc0 = ((const f4*)Wc)[tx * 2];
  f4 wc1 = ((const f4*)Wc)[tx * 2 + 1];
  float bcv = bc[0];
  #pragma unroll
  for (int i = 0; i < 8; ++i) {
    f4 a = accA[i], b = accB[i];
    RELU4(a) RELU4(b)
    float s = a.x * wc0.x + a.y * wc0.y + a.z * wc0.z + a.w * wc0.w
            + b.x * wc1.x + b.y * wc1.y + b.z * wc1.z + b.w * wc1.w;
    s += __shfl_xor(s, 1, 64);
    s += __shfl_xor(s, 2, 64);
    s += __shfl_xor(s, 4, 64);
    int node = n0 + ng * 8 + i;
    if (tx == 0 && node < n) out[node] = s + bcv;
  }
}

extern "C" void kernel_launch(void* const* d_in, const int* in_sizes, int n_in,
                              void* d_out, int out_size, void* d_ws, size_t ws_size,
                              hipStream_t stream) {
  const float* x   = (const float*)d_in[0];
  const int*   ei  = (const int*)d_in[1];
  const float* Wp  = (const float*)d_in[2];
  const float* bp  = (const float*)d_in[3];
  const float* W1l = (const float*)d_in[4];
  const float* b1l = (const float*)d_in[5];
  const float* W1r = (const float*)d_in[6];
  const float* W2l = (const float*)d_in[7];
  const float* b2l = (const float*)d_in[8];
  const float* W2r = (const float*)d_in[9];
  const float* Wc  = (const float*)d_in[10];
  const float* bc  = (const float*)d_in[11];
  float* out = (float*)d_out;

  const int N = NNODES, E = NEDGES;
  const int* src = ei;
  const int* dst = ei + E;

  char* ws = (char*)d_ws;
  float* h       = (float*)(ws + 0);
  float* aggr    = (float*)(ws + 51200000);
  int*   counts  = (int*)  (ws + 102400000);
  int*   row_ptr = (int*)  (ws + 103200000);
  int*   cursor  = (int*)  (ws + 104000256);
  int*   csr_src = (int*)  (ws + 104800256);
  int*   bsums   = (int*)  (ws + 117600256);

  hipMemsetAsync(counts, 0, (size_t)N * 4, stream);

  proj_kernel<<<782, 256, 0, stream>>>(x, Wp, bp, h, N);

  int nchunks = (E + CHUNK_E - 1) / CHUNK_E;
  degree_kernel<<<nchunks * NR, 256, 0, stream>>>(dst, counts, E);
  int nb = (N + SCAN_CHUNK - 1) / SCAN_CHUNK;
  scan1_kernel<<<nb, SCAN_T, 0, stream>>>(counts, row_ptr, bsums, N);
  scan2_kernel<<<1, SCAN_T, 0, stream>>>(bsums, nb);
  scan3_kernel<<<(N + 256) / 256, 256, 0, stream>>>(row_ptr, bsums, cursor, N, E);
  scatter_kernel<<<nchunks * NR, 256, 0, stream>>>(src, dst, cursor, csr_src, E);

  aggr_kernel<<<(N + 3) / 4, 256, 0, stream>>>(h, row_ptr, csr_src, aggr, N);
  gemm_kernel<<<782, 256, 0, stream>>>(aggr, h, W1l, b1l, W1r, h, N);

  aggr_kernel<<<(N + 3) / 4, 256, 0, stream>>>(h, row_ptr, csr_src, aggr, N);
  gemm_cls_kernel<<<782, 256, 0, stream>>>(aggr, h, W2l, b2l, W2r, Wc, bc, out, N);
}